// Round 5
// baseline (183923.010 us; speedup 1.0000x reference)
//
#include <hip/hip_runtime.h>
#include <stdint.h>

// Problem: D-FPS. points_xyz (16, 131072, 3) fp32 -> indices (16, 4096) int32.
#define BATCH 16
#define NPTS  131072
#define NSAMP 4096
#define NBLK  16                  // blocks per batch (sync participants)
#define TPB   512                 // 8 waves; launch_bounds(512,2) -> 256 VGPR budget
#define CHUNK (NPTS / NBLK)       // 8192 points per block
#define PPT   (CHUNK / TPB)       // 16 points per thread, register-resident
#define NWAVE (TPB / 64)          // 8 waves per block

// Tagged slot (8B): [63:32] dist bits | [31:15] idx (17b) | [14:0] iter tag.
// Poison 0xAA.. -> tag 0x2AAA; zero-init -> 0; neither is a live it in [1,4095].
// Ring-2 by parity. Happens-before audit (all-waves-read-gs variant):
//   block B stores gs tag I+2  <-  B.wave0 saw all red tagged I+2 in LDS
//   <- every wave of B stored red I+2 <- each finished its gs poll of I+1
//   <- every block's gs store tag I+1 <- that block's wave0 saw red I+1 from
//   ALL its waves <- each of those waves finished reading gs tags I.
// So no slot is overwritten with tag I+2 before all tag-I readers are done.

static __device__ __forceinline__ unsigned long long
pack_tagged(unsigned int distBits, unsigned int idx, int it) {
    return ((unsigned long long)distBits << 32) |
           ((unsigned long long)idx << 15) | (unsigned long long)it;
}
// Comparison key: max dist, then min index (jnp.argmax first-occurrence).
static __device__ __forceinline__ unsigned long long
tagged_to_key(unsigned long long v) {
    unsigned int db  = (unsigned int)(v >> 32);
    unsigned int idx = (unsigned int)((v >> 15) & 0x1FFFFu);
    return ((unsigned long long)db << 32) | (unsigned long long)(~idx);
}

__global__ void fps_init_kernel(unsigned long long* __restrict__ gslot) {
    int i = blockIdx.x * blockDim.x + threadIdx.x;
    if (i < BATCH * 2 * NBLK) gslot[i] = 0ull;
}

__global__ __launch_bounds__(TPB, 2) void fps_kernel(
        const float* __restrict__ xyz, int* __restrict__ out,
        unsigned long long* __restrict__ gslot) {
    const int blk   = blockIdx.x;
    const int b     = blk & 15;        // batch = blk%16: a batch's blocks share
    const int chunk = blk >> 4;        // blockIdx%8 -> XCD co-location heuristic
    const int tid   = threadIdx.x;
    const int lane  = tid & 63;

    const float* bxyz = xyz + (size_t)b * NPTS * 3;
    const int base = chunk * CHUNK;

    // Register-resident points + running min distance.
    // TPB=512 + launch_bounds(512,2) -> 256-VGPR budget: ~94 live regs fit
    // with huge slack, so the allocator has no spill incentive (rounds 3/4
    // shipped VGPR_Count=28 under the 128-reg budget: points were NEVER
    // register-resident; this is the fix).
    float px[PPT], py[PPT], pz[PPT], pd[PPT];
#pragma unroll
    for (int k = 0; k < PPT; ++k) {
        int p = base + tid + k * TPB;
        px[k] = bxyz[3 * (size_t)p + 0];
        py[k] = bxyz[3 * (size_t)p + 1];
        pz[k] = bxyz[3 * (size_t)p + 2];
        pd[k] = __builtin_inff();
    }
    // Forbid rematerialization: values become asm-defined. Split into 16-operand
    // groups to stay under inline-asm constraint limits.
#define PIN8(a)  "+v"(a[0]), "+v"(a[1]), "+v"(a[2]), "+v"(a[3]), \
                 "+v"(a[4]), "+v"(a[5]), "+v"(a[6]), "+v"(a[7])
#define PIN16(a) PIN8(a), "+v"(a[8]), "+v"(a[9]), "+v"(a[10]), "+v"(a[11]), \
                 "+v"(a[12]), "+v"(a[13]), "+v"(a[14]), "+v"(a[15])
    asm volatile("" : PIN16(px));
    asm volatile("" : PIN16(py));
    asm volatile("" : PIN16(pz));
#undef PIN16
#undef PIN8

    __shared__ unsigned long long red[2][NWAVE];  // per-wave tagged bests
    if (tid < 2 * NWAVE) ((unsigned long long*)red)[tid] = ~0ull; // invalid tag
    if (tid == 0 && chunk == 0) out[b * NSAMP] = 0;  // iteration 0 emits idx 0
    __syncthreads();  // the only block-wide barrier (LDS init)

    float cx = bxyz[0], cy = bxyz[1], cz = bxyz[2];

    unsigned long long* gs = gslot + (size_t)b * 2 * NBLK;  // [2][NBLK]

    for (int it = 1; it < NSAMP; ++it) {
        const int par = it & 1;

        // ---- update min-dists + local argmax (registers only) ----
        // Verified arithmetic (round 2, absmax 0): FMA-contracted
        //   d = fma(dz,dz, fma(dy,dy, dx*dx)), subs exact-rounded.
        float bd = -1.0f;           // all dists >= 0
        int   bk = 0;
#pragma unroll
        for (int k = 0; k < PPT; ++k) {
            float dx = __fsub_rn(px[k], cx);
            float dy = __fsub_rn(py[k], cy);
            float dz = __fsub_rn(pz[k], cz);
            float d  = __builtin_fmaf(dz, dz,
                         __builtin_fmaf(dy, dy, __fmul_rn(dx, dx)));
            float nd = fminf(pd[k], d);
            pd[k] = nd;
            // strict > keeps earliest k (gi ascends with k) -> first-occurrence
            if (nd > bd) { bd = nd; bk = k; }
        }
        unsigned int gi = (unsigned int)(base + tid + bk * TPB);
        unsigned long long key =
            ((unsigned long long)__float_as_uint(bd) << 32) |
            (unsigned long long)(~gi);

        // ---- wave butterfly (64 lanes, 6 steps) ----
#pragma unroll
        for (int off = 1; off <= 32; off <<= 1) {
            unsigned long long o = __shfl_xor(key, off, 64);
            key = key > o ? key : o;
        }
        if (lane == 0) {
            unsigned int db  = (unsigned int)(key >> 32);
            unsigned int idx = ~(unsigned int)key;  // recover gi (17 bits)
            __hip_atomic_store(&red[par][tid >> 6], pack_tagged(db, idx, it),
                               __ATOMIC_RELEASE, __HIP_MEMORY_SCOPE_WORKGROUP);
        }

        // ---- ALL waves: poll the 8 LDS wave-slots, reduce to block winner ----
        unsigned long long v; bool ok;
        do {
            v  = (lane < NWAVE)
                   ? __hip_atomic_load(&red[par][lane], __ATOMIC_ACQUIRE,
                                       __HIP_MEMORY_SCOPE_WORKGROUP)
                   : 0ull;
            ok = (lane < NWAVE) ? ((v & 0x7FFFull) == (unsigned long long)it)
                                : true;
        } while (__ballot(ok) != ~0ull);
        unsigned long long k2 = (lane < NWAVE) ? tagged_to_key(v) : 0ull;
#pragma unroll
        for (int off = 1; off <= 4; off <<= 1) {
            unsigned long long o = __shfl_xor(k2, off, 64);
            k2 = k2 > o ? k2 : o;
        }
        // wave 0 lane 0 publishes the block winner (one agent release store)
        if (tid == 0) {
            unsigned int db  = (unsigned int)(k2 >> 32);
            unsigned int idx = ~(unsigned int)k2;
            __hip_atomic_store(&gs[par * NBLK + chunk],
                               pack_tagged(db, idx, it),
                               __ATOMIC_RELEASE, __HIP_MEMORY_SCOPE_AGENT);
        }

        // ---- ALL waves: poll the 16 global slots directly (no rebroadcast) --
        do {
            v  = (lane < NBLK)
                   ? __hip_atomic_load(&gs[par * NBLK + lane], __ATOMIC_ACQUIRE,
                                       __HIP_MEMORY_SCOPE_AGENT)
                   : 0ull;
            ok = (lane < NBLK) ? ((v & 0x7FFFull) == (unsigned long long)it)
                               : true;
        } while (__ballot(ok) != ~0ull);

        // Prefetch all 16 candidates' coords BEFORE the winner is known;
        // after the butterfly, 3 shuffles replace a dependent L2 load.
        unsigned int ci = (lane < NBLK) ? (unsigned int)((v >> 15) & 0x1FFFFu)
                                        : 0u;
        float fx = bxyz[3 * (size_t)ci + 0];
        float fy = bxyz[3 * (size_t)ci + 1];
        float fz = bxyz[3 * (size_t)ci + 2];

        unsigned long long k3o = (lane < NBLK) ? tagged_to_key(v) : 0ull;
        unsigned long long k3 = k3o;
#pragma unroll
        for (int off = 1; off <= 32; off <<= 1) {   // full 6-step: winner on ALL lanes
            unsigned long long o = __shfl_xor(k3, off, 64);
            k3 = k3 > o ? k3 : o;
        }
        // exactly one lane holds the winning candidate (indices are distinct)
        unsigned long long mine = __ballot((lane < NBLK) && (k3o == k3));
        int wl = (int)__builtin_ctzll(mine);
        cx = __shfl(fx, wl, 64);
        cy = __shfl(fy, wl, 64);
        cz = __shfl(fz, wl, 64);

        if (tid == 0 && chunk == 0)
            out[b * NSAMP + it] = (int)(~(unsigned int)k3);
    }
}

extern "C" void kernel_launch(void* const* d_in, const int* in_sizes, int n_in,
                              void* d_out, int out_size, void* d_ws, size_t ws_size,
                              hipStream_t stream) {
    const float* xyz = (const float*)d_in[0];
    int* out = (int*)d_out;
    unsigned long long* gslot = (unsigned long long*)d_ws;  // [BATCH][2][NBLK]

    hipLaunchKernelGGL(fps_init_kernel, dim3(1), dim3(512), 0, stream, gslot);
    hipLaunchKernelGGL(fps_kernel, dim3(BATCH * NBLK), dim3(TPB), 0, stream,
                       xyz, out, gslot);
}

// Round 6
// 69594.452 us; speedup vs baseline: 2.6428x; 2.6428x over previous
//
#include <hip/hip_runtime.h>
#include <stdint.h>

// Problem: D-FPS. points_xyz (16, 131072, 3) fp32 -> indices (16, 4096) int32.
//
// Design (round 6): points staged in LDS as padded float4 (ds_read_b128,
// stride-16 = measured-conflict-free pattern). The register-residency path is
// dead: r3/r4/r5 all shipped with the allocator rematerializing or scratch-
// spilling the coordinate arrays regardless of pins/budgets. LDS is
// deterministic. Cross-block sync: ONE polling wave per block (r5 proved
// all-wave agent-scope polling convoys catastrophically), LDS fan-out.

#define BATCH   16
#define NSAMP   4096
#define NPTS    131072
#define NBLK    32                 // blocks per batch
#define TPB     512                // 8 waves
#define CHUNK   (NPTS / NBLK)      // 4096 points per block
#define LDSPTS  4064               // points staged in LDS (float4 = 65024 B)
#define STRIDE  508                // LDSPTS/8: thread t<508 owns t+508k, k<8
#define EXTRA   (CHUNK - LDSPTS)   // 32 leftover pts: wave0 lanes, reg-resident
#define NWAVE   (TPB / 64)

// Tagged slot (8B): [63:32] dist bits | [31:15] idx (17b) | [14:0] iter tag.
// Poison 0xAA.. -> tag 0x2AAA; zero-init -> 0; LDS init ~0 -> 0x7FFF; none is
// a live it in [1,4095]. Ring-2 by parity; happens-before chain (r3-audited):
// a slot's tag-I readers all complete before any tag-I+2 overwrite, because
// each block's I+2 publication is gated behind every block's I+1 publication,
// which is gated behind that block's completed iter-I reads.

static __device__ __forceinline__ unsigned long long
pack_tagged(unsigned int distBits, unsigned int idx, int it) {
    return ((unsigned long long)distBits << 32) |
           ((unsigned long long)idx << 15) | (unsigned long long)it;
}
// Comparison key: max dist, then min index (jnp.argmax first-occurrence).
static __device__ __forceinline__ unsigned long long
tagged_to_key(unsigned long long v) {
    unsigned int db  = (unsigned int)(v >> 32);
    unsigned int idx = (unsigned int)((v >> 15) & 0x1FFFFu);
    return ((unsigned long long)db << 32) | (unsigned long long)(~idx);
}

__global__ void fps_init_kernel(unsigned long long* __restrict__ gslot) {
    int i = blockIdx.x * blockDim.x + threadIdx.x;
    if (i < BATCH * 2 * NBLK) gslot[i] = 0ull;
}

__global__ __launch_bounds__(TPB, 4) void fps_kernel(
        const float* __restrict__ xyz, int* __restrict__ out,
        unsigned long long* __restrict__ gslot) {
    const int blk   = blockIdx.x;
    const int b     = blk & 15;        // batch = blk%16: blk%8 constant per
    const int chunk = blk >> 4;        // batch -> XCD co-location heuristic
    const int tid   = threadIdx.x;
    const int w     = tid >> 6;
    const int lane  = tid & 63;

    const float* bxyz = xyz + (size_t)b * NPTS * 3;
    const int base = chunk * CHUNK;

    // ---- LDS staging: 4064 points as float4 (x,y,z,unused) ----
    __shared__ float4 pts[LDSPTS];                 // 65024 B
    __shared__ unsigned long long red[2][NWAVE];   // 128 B
    __shared__ unsigned long long bcA[2], bcB[2];  // 32 B   (total 65184)
    for (int i = tid; i < LDSPTS; i += TPB) {
        int p = base + i;
        pts[i] = make_float4(bxyz[3 * (size_t)p + 0],
                             bxyz[3 * (size_t)p + 1],
                             bxyz[3 * (size_t)p + 2], 0.0f);
    }
    if (tid < 2 * NWAVE) ((unsigned long long*)red)[tid] = ~0ull;
    if (tid < 2) { bcA[tid] = ~0ull; bcB[tid] = ~0ull; }
    if (tid == 0 && chunk == 0) out[b * NSAMP] = 0;   // iter 0 emits index 0
    __syncthreads();   // the only block barrier (staging visibility)

    // 32 leftover points live on wave0 lanes 0..31: their coords are
    // loop-invariant global loads (3 scalars -> compiler hoists into 3 VGPRs;
    // small enough that the allocator has always kept such values resident).
    float ex = 0.f, ey = 0.f, ez = 0.f, pdx = __builtin_inff();
    unsigned int egi = 0;
    if (tid < EXTRA) {
        egi = (unsigned int)(base + LDSPTS + tid);
        ex = bxyz[3 * (size_t)egi + 0];
        ey = bxyz[3 * (size_t)egi + 1];
        ez = bxyz[3 * (size_t)egi + 2];
    }

    float pd[8];
#pragma unroll
    for (int k = 0; k < 8; ++k) pd[k] = __builtin_inff();

    float cx = bxyz[0], cy = bxyz[1], cz = bxyz[2];

    unsigned long long* gs = gslot + (size_t)b * 2 * NBLK;  // [2][NBLK]

    for (int it = 1; it < NSAMP; ++it) {
        const int par = it & 1;

        // ---- update min-dists + local argmax ----
        // Verified arithmetic (round 2, absmax 0): FMA-contracted
        //   d = fma(dz,dz, fma(dy,dy, dx*dx)), subs exact-rounded.
        unsigned long long key = 0ull;   // empty threads contribute 0
        if (tid < STRIDE) {
            float bd = -1.0f;
            int   bk = 0;
#pragma unroll
            for (int k = 0; k < 8; ++k) {
                float4 p = pts[tid + STRIDE * k];   // ds_read_b128, stride-16
                float dx = __fsub_rn(p.x, cx);
                float dy = __fsub_rn(p.y, cy);
                float dz = __fsub_rn(p.z, cz);
                float d  = __builtin_fmaf(dz, dz,
                             __builtin_fmaf(dy, dy, __fmul_rn(dx, dx)));
                float nd = fminf(pd[k], d);
                pd[k] = nd;
                // strict >: earliest k wins (gi ascends with k) = first-occur.
                if (nd > bd) { bd = nd; bk = k; }
            }
            unsigned int gi = (unsigned int)(base + tid + STRIDE * bk);
            key = ((unsigned long long)__float_as_uint(bd) << 32) |
                  (unsigned long long)(~gi);
        }
        if (tid < EXTRA) {
            float dx = __fsub_rn(ex, cx);
            float dy = __fsub_rn(ey, cy);
            float dz = __fsub_rn(ez, cz);
            float d  = __builtin_fmaf(dz, dz,
                         __builtin_fmaf(dy, dy, __fmul_rn(dx, dx)));
            pdx = fminf(pdx, d);
            unsigned long long ek =
                ((unsigned long long)__float_as_uint(pdx) << 32) |
                (unsigned long long)(~egi);
            key = key > ek ? key : ek;
        }

        // ---- wave butterfly (64 lanes) ----
#pragma unroll
        for (int off = 1; off <= 32; off <<= 1) {
            unsigned long long o = __shfl_xor(key, off, 64);
            key = key > o ? key : o;
        }
        if (lane == 0) {
            unsigned int db  = (unsigned int)(key >> 32);
            unsigned int idx = ~(unsigned int)key;
            __hip_atomic_store(&red[par][w], pack_tagged(db, idx, it),
                               __ATOMIC_RELEASE, __HIP_MEMORY_SCOPE_WORKGROUP);
        }

        if (w == 0) {
            // ---- wave0 only: combine 8 wave entries from LDS ----
            unsigned long long v; bool ok;
            do {
                v  = (lane < NWAVE)
                       ? __hip_atomic_load(&red[par][lane], __ATOMIC_ACQUIRE,
                                           __HIP_MEMORY_SCOPE_WORKGROUP)
                       : 0ull;
                ok = (lane < NWAVE) ? ((v & 0x7FFFull) == (unsigned long long)it)
                                    : true;
            } while (__ballot(ok) != ~0ull);
            unsigned long long k2 = (lane < NWAVE) ? tagged_to_key(v) : 0ull;
#pragma unroll
            for (int off = 1; off <= 4; off <<= 1) {
                unsigned long long o = __shfl_xor(k2, off, 64);
                k2 = k2 > o ? k2 : o;
            }
            if (lane == 0) {
                unsigned int db  = (unsigned int)(k2 >> 32);
                unsigned int idx = ~(unsigned int)k2;
                __hip_atomic_store(&gs[par * NBLK + chunk],
                                   pack_tagged(db, idx, it),
                                   __ATOMIC_RELEASE, __HIP_MEMORY_SCOPE_AGENT);
            }
            // ---- wave0 only: poll the 32 block slots (r5 lesson: ONE wave) --
            do {
                v  = (lane < NBLK)
                       ? __hip_atomic_load(&gs[par * NBLK + lane],
                                           __ATOMIC_ACQUIRE,
                                           __HIP_MEMORY_SCOPE_AGENT)
                       : 0ull;
                ok = (lane < NBLK) ? ((v & 0x7FFFull) == (unsigned long long)it)
                                   : true;
            } while (__ballot(ok) != ~0ull);

            // Prefetch all 32 candidates' coords BEFORE the winner is known;
            // 3 shuffles then replace a dependent L2 load.
            unsigned int ci = (lane < NBLK)
                                  ? (unsigned int)((v >> 15) & 0x1FFFFu) : 0u;
            float fx = bxyz[3 * (size_t)ci + 0];
            float fy = bxyz[3 * (size_t)ci + 1];
            float fz = bxyz[3 * (size_t)ci + 2];

            unsigned long long k3o = (lane < NBLK) ? tagged_to_key(v) : 0ull;
            unsigned long long k3 = k3o;
#pragma unroll
            for (int off = 1; off <= 16; off <<= 1) {  // lanes 0..31 combined
                unsigned long long o = __shfl_xor(k3, off, 64);
                k3 = k3 > o ? k3 : o;
            }
            unsigned long long mine = __ballot((lane < NBLK) && (k3o == k3));
            int wl = (int)__builtin_ctzll(mine);
            cx = __shfl(fx, wl, 64);
            cy = __shfl(fy, wl, 64);
            cz = __shfl(fz, wl, 64);
            unsigned int widx = __shfl(ci, wl, 64);

            if (lane == 0) {
                if (chunk == 0) out[b * NSAMP + it] = (int)widx;
                // coords first (relaxed), then tag word (release)
                __hip_atomic_store(&bcA[par],
                    ((unsigned long long)__float_as_uint(cx) << 32) |
                        (unsigned long long)__float_as_uint(cy),
                    __ATOMIC_RELAXED, __HIP_MEMORY_SCOPE_WORKGROUP);
                __hip_atomic_store(&bcB[par],
                    ((unsigned long long)__float_as_uint(cz) << 32) |
                        ((unsigned long long)(unsigned int)it << 17) |
                        (unsigned long long)widx,
                    __ATOMIC_RELEASE, __HIP_MEMORY_SCOPE_WORKGROUP);
            }
        } else {
            // ---- other waves: wait for tagged broadcast ----
            unsigned long long bv;
            do {
                bv = __hip_atomic_load(&bcB[par], __ATOMIC_ACQUIRE,
                                       __HIP_MEMORY_SCOPE_WORKGROUP);
            } while (((bv >> 17) & 0x7FFFull) != (unsigned long long)it);
            unsigned long long av =
                __hip_atomic_load(&bcA[par], __ATOMIC_RELAXED,
                                  __HIP_MEMORY_SCOPE_WORKGROUP);
            cz = __uint_as_float((unsigned int)(bv >> 32));
            cx = __uint_as_float((unsigned int)(av >> 32));
            cy = __uint_as_float((unsigned int)av);
        }
    }
}

extern "C" void kernel_launch(void* const* d_in, const int* in_sizes, int n_in,
                              void* d_out, int out_size, void* d_ws, size_t ws_size,
                              hipStream_t stream) {
    const float* xyz = (const float*)d_in[0];
    int* out = (int*)d_out;
    unsigned long long* gslot = (unsigned long long*)d_ws;  // [BATCH][2][NBLK]

    hipLaunchKernelGGL(fps_init_kernel, dim3(4), dim3(256), 0, stream, gslot);
    hipLaunchKernelGGL(fps_kernel, dim3(BATCH * NBLK), dim3(TPB), 0, stream,
                       xyz, out, gslot);
}